// Round 1
// baseline (4218.167 us; speedup 1.0000x reference)
//
#include <hip/hip_runtime.h>

// ---------------------------------------------------------------------------
// LlamaDecoderLayerDAT — correctness-first all-fp32 baseline.
// Pipeline:
//   1. q/k/v = hs @ w{q,k,v}.T                       (gemm_nt)
//   2. offset net: lr grid -> dwconv3x3+silu -> LN(512) -> 1x1 conv(->64)
//      gate = sigmoid(pool @ piw.T + pib); LN(64) -> 1x1 conv(->2) -> tanh
//   3. bilinear sample HD grid at pos -> samp [B,K,C]
//   4. k_hd/v_hd = samp @ w.T + b                    (gemm_nt)
//   5. flash attention (causal text keys 0..1023, HD keys 1024..1599 visible)
//   6. out = attn @ wo.T                             (gemm_nt)
// Workspace layout (floats): q, k_txt, v_txt, attn_out (4x 4194304),
//   k_hd, v_hd (2x 2359296), lr (2359296, reused for samp), x1 (2359296),
//   x2 (294912), pooled, gate, pos  => ~106 MB total.
// ---------------------------------------------------------------------------

constexpr int B = 2;
constexpr int NQ = 1024;
constexpr int C = 2048;
constexpr int H = 16;
constexpr int DH = 128;
constexpr int G = 4;
constexpr int CD = 512;
constexpr int LR = 24;
constexpr int HR = 72;
constexpr int INTER = 64;
constexpr int K = LR * LR;   // 576

// ------------------------------ GEMM (NT, fp32) -----------------------------
constexpr int TS = 64;
constexpr int KT = 16;

__global__ __launch_bounds__(256) void gemm_nt(
    const float* __restrict__ A, const float* __restrict__ W,
    const float* __restrict__ bias, float* __restrict__ out,
    int M, int N, int Kd) {
  __shared__ float As[TS][KT + 1];
  __shared__ float Ws[TS][KT + 1];
  const int tid = threadIdx.x;
  const int tx = tid & 15, ty = tid >> 4;
  const int m0 = blockIdx.y * TS, n0 = blockIdx.x * TS;
  float acc[4][4] = {};
  for (int c0 = 0; c0 < Kd; c0 += KT) {
    for (int i = tid; i < TS * KT; i += 256) {
      int r = i >> 4, k = i & 15;
      int mr = m0 + r;
      As[r][k] = (mr < M) ? A[(size_t)mr * Kd + c0 + k] : 0.f;
      Ws[r][k] = W[(size_t)(n0 + r) * Kd + c0 + k];
    }
    __syncthreads();
#pragma unroll
    for (int k = 0; k < KT; ++k) {
      float a[4], b[4];
#pragma unroll
      for (int i = 0; i < 4; ++i) a[i] = As[ty + i * 16][k];
#pragma unroll
      for (int j = 0; j < 4; ++j) b[j] = Ws[tx + j * 16][k];
#pragma unroll
      for (int i = 0; i < 4; ++i)
#pragma unroll
        for (int j = 0; j < 4; ++j) acc[i][j] += a[i] * b[j];
    }
    __syncthreads();
  }
#pragma unroll
  for (int i = 0; i < 4; ++i) {
    int m = m0 + ty + i * 16;
    if (m >= M) continue;
#pragma unroll
    for (int j = 0; j < 4; ++j) {
      int n = n0 + tx + j * 16;
      float v = acc[i][j];
      if (bias) v += bias[n];
      out[(size_t)m * N + n] = v;
    }
  }
}

// ----------------------- offset network (tiny kernels) ----------------------
// lr[n=b*4+g][c][p=y*24+x] = hs[b][p][g*512+c]
__global__ __launch_bounds__(256) void build_lr(const float* __restrict__ hs,
                                                float* __restrict__ lr) {
  int idx = blockIdx.x * 256 + threadIdx.x;
  if (idx >= B * G * CD * K) return;
  int p = idx % K;
  int c = (idx / K) % CD;
  int n = idx / (K * CD);
  int b = n >> 2, g = n & 3;
  lr[idx] = hs[((size_t)b * NQ + p) * C + g * CD + c];
}

__global__ __launch_bounds__(256) void pool_lr(const float* __restrict__ lr,
                                               float* __restrict__ pooled) {
  int idx = blockIdx.x * 256 + threadIdx.x;
  if (idx >= B * G * CD) return;
  const float* p = lr + (size_t)idx * K;
  float s = 0.f;
  for (int i = 0; i < K; ++i) s += p[i];
  pooled[idx] = s * (1.f / K);
}

__global__ __launch_bounds__(256) void dwconv_silu(const float* __restrict__ lr,
                                                   const float* __restrict__ w,
                                                   float* __restrict__ x1) {
  int idx = blockIdx.x * 256 + threadIdx.x;
  if (idx >= B * G * CD * K) return;
  int p = idx % K;
  int c = (idx / K) % CD;
  int n = idx / (K * CD);
  int y = p / LR, x = p % LR;
  const float* wp = w + c * 9;
  const float* src = lr + ((size_t)n * CD + c) * K;
  float s = 0.f;
#pragma unroll
  for (int dy = -1; dy <= 1; ++dy)
#pragma unroll
    for (int dx = -1; dx <= 1; ++dx) {
      int yy = y + dy, xx = x + dx;
      if (yy < 0 || yy >= LR || xx < 0 || xx >= LR) continue;
      s += src[yy * LR + xx] * wp[(dy + 1) * 3 + dx + 1];
    }
  x1[idx] = s / (1.f + expf(-s));  // silu
}

// channel LayerNorm over 512, in-place. one block per pixel (n,p).
__global__ __launch_bounds__(256) void ln_c512(float* __restrict__ x,
                                               const float* __restrict__ w,
                                               const float* __restrict__ b) {
  const int n = blockIdx.x / K;
  const int p = blockIdx.x % K;
  float* base = x + ((size_t)n * CD) * K + p;
  const int tid = threadIdx.x;
  const float v0 = base[(size_t)tid * K];
  const float v1 = base[(size_t)(tid + 256) * K];
  float s = v0 + v1, ss = v0 * v0 + v1 * v1;
  for (int o = 32; o; o >>= 1) {
    s += __shfl_down(s, o);
    ss += __shfl_down(ss, o);
  }
  __shared__ float rs[4], rss[4];
  const int wave = tid >> 6, lane = tid & 63;
  if (lane == 0) { rs[wave] = s; rss[wave] = ss; }
  __syncthreads();
  if (tid == 0) {
    rs[0] = rs[0] + rs[1] + rs[2] + rs[3];
    rss[0] = rss[0] + rss[1] + rss[2] + rss[3];
  }
  __syncthreads();
  const float mean = rs[0] * (1.f / CD);
  const float var = rss[0] * (1.f / CD) - mean * mean;
  const float inv = rsqrtf(var + 1e-5f);
  base[(size_t)tid * K] = (v0 - mean) * inv * w[tid] + b[tid];
  base[(size_t)(tid + 256) * K] = (v1 - mean) * inv * w[tid + 256] + b[tid + 256];
}

// x2[n][o][p] = sum_c x1[n][c][p] * w[o][c] ; block=(n,o), thread=p (576)
__global__ __launch_bounds__(576) void proj64(const float* __restrict__ x1,
                                              const float* __restrict__ w,
                                              float* __restrict__ x2) {
  const int n = blockIdx.x >> 6;
  const int o = blockIdx.x & 63;
  const int p = threadIdx.x;
  const float* xb = x1 + (size_t)n * CD * K + p;
  const float* wb = w + o * CD;
  float s = 0.f;
  for (int c = 0; c < CD; ++c) s += xb[(size_t)c * K] * wb[c];
  x2[((size_t)n * INTER + o) * K + p] = s;
}

__global__ __launch_bounds__(64) void gate_k(const float* __restrict__ pooled,
                                             const float* __restrict__ w,
                                             const float* __restrict__ bias,
                                             float* __restrict__ gate) {
  int idx = blockIdx.x * 64 + threadIdx.x;
  if (idx >= B * G * INTER) return;
  int n = idx >> 6, o = idx & 63;
  const float* pb = pooled + n * CD;
  const float* wb = w + o * CD;
  float s = bias[o];
  for (int c = 0; c < CD; ++c) s += pb[c] * wb[c];
  gate[idx] = 1.f / (1.f + expf(-s));
}

// gate*x2 -> LN(64) -> conv_off -> pos=tanh(ref+off). one wave per pixel.
__global__ __launch_bounds__(256) void ln2_off_pos(
    const float* __restrict__ x2, const float* __restrict__ gate,
    const float* __restrict__ ln2w, const float* __restrict__ ln2b,
    const float* __restrict__ offw, float* __restrict__ pos) {
  int wid = (blockIdx.x * 256 + threadIdx.x) >> 6;
  int lane = threadIdx.x & 63;
  if (wid >= B * G * K) return;
  int n = wid / K, p = wid % K;
  float v = x2[((size_t)n * INTER + lane) * K + p] * gate[n * INTER + lane];
  float s = v, ss = v * v;
  for (int o = 32; o; o >>= 1) {
    s += __shfl_xor(s, o);
    ss += __shfl_xor(ss, o);
  }
  float mean = s * (1.f / INTER);
  float var = ss * (1.f / INTER) - mean * mean;
  float xn = (v - mean) * rsqrtf(var + 1e-5f) * ln2w[lane] + ln2b[lane];
  float ox = xn * offw[lane];        // component 0 (x)
  float oy = xn * offw[INTER + lane];// component 1 (y)
  for (int o = 32; o; o >>= 1) {
    ox += __shfl_xor(ox, o);
    oy += __shfl_xor(oy, o);
  }
  if (lane == 0) {
    int yi = p / LR, xi = p % LR;
    float rx = (xi + 0.5f) / 23.f * 2.f - 1.f;
    float ry = (yi + 0.5f) / 23.f * 2.f - 1.f;
    pos[((size_t)n * K + p) * 2 + 0] = tanhf(rx + ox);
    pos[((size_t)n * K + p) * 2 + 1] = tanhf(ry + oy);
  }
}

// bilinear sample from image_hd directly into [B,K,C]; one block per (b,k)
__global__ __launch_bounds__(256) void sample_k(const float* __restrict__ img,
                                                const float* __restrict__ pos,
                                                float* __restrict__ samp) {
  const int bk = blockIdx.x;
  const int b = bk / K, k = bk % K;
  __shared__ int s_idx[G][4];
  __shared__ float s_w[G][4];
  if (threadIdx.x < G) {
    int g = threadIdx.x;
    int n = b * G + g;
    float px = pos[((size_t)n * K + k) * 2 + 0];
    float py = pos[((size_t)n * K + k) * 2 + 1];
    float x = (px + 1.f) * 0.5f * (HR - 1);
    float y = (py + 1.f) * 0.5f * (HR - 1);
    float x0f = floorf(x), y0f = floorf(y);
    float wx = x - x0f, wy = y - y0f;
    int x0 = min(max((int)x0f, 0), HR - 1);
    int x1 = min(x0 + 1, HR - 1);
    int y0 = min(max((int)y0f, 0), HR - 1);
    int y1 = min(y0 + 1, HR - 1);
    s_idx[g][0] = y0 * HR + x0;
    s_idx[g][1] = y0 * HR + x1;
    s_idx[g][2] = y1 * HR + x0;
    s_idx[g][3] = y1 * HR + x1;
    s_w[g][0] = (1.f - wx) * (1.f - wy);
    s_w[g][1] = wx * (1.f - wy);
    s_w[g][2] = (1.f - wx) * wy;
    s_w[g][3] = wx * wy;
  }
  __syncthreads();
  const float* ib = img + (size_t)b * HR * HR * C;
  float* ob = samp + ((size_t)b * K + k) * C;
  for (int ch = threadIdx.x; ch < C; ch += 256) {
    int g = ch >> 9;
    float v = s_w[g][0] * ib[(size_t)s_idx[g][0] * C + ch] +
              s_w[g][1] * ib[(size_t)s_idx[g][1] * C + ch] +
              s_w[g][2] * ib[(size_t)s_idx[g][2] * C + ch] +
              s_w[g][3] * ib[(size_t)s_idx[g][3] * C + ch];
    ob[ch] = v;
  }
}

// ------------------------------ flash attention -----------------------------
constexpr int TQ = 32;
constexpr int TK = 32;

__global__ __launch_bounds__(256) void attn_k(
    const float* __restrict__ q, const float* __restrict__ ktxt,
    const float* __restrict__ vtxt, const float* __restrict__ khd,
    const float* __restrict__ vhd, float* __restrict__ outp) {
  const int b = blockIdx.z, h = blockIdx.y;
  const int q0 = blockIdx.x * TQ;
  __shared__ float Qs[TQ][DH + 1];
  __shared__ float Ks[TK][DH + 1];
  __shared__ float Vs[TK][DH + 1];
  __shared__ float Ss[TQ][TK + 1];
  __shared__ float row_m[TQ], row_l[TQ], row_f[TQ];
  const int tid = threadIdx.x;

  for (int i = tid; i < TQ * DH; i += 256) {
    int r = i >> 7, d = i & (DH - 1);
    Qs[r][d] = q[((size_t)b * NQ + q0 + r) * C + h * DH + d];
  }
  if (tid < TQ) { row_m[tid] = -1e30f; row_l[tid] = 0.f; }

  float acc[16];
#pragma unroll
  for (int i = 0; i < 16; ++i) acc[i] = 0.f;
  const int my_r = tid >> 3;
  const int my_d0 = (tid & 7) * 16;

  const int n_text = (q0 + TQ - 1) / TK + 1;  // text tiles needed for causality
  const int total = n_text + K / TK;          // + 18 HD tiles
  const float scale = 0.088388347648318447f;  // 1/sqrt(128)

  for (int t = 0; t < total; ++t) {
    const bool is_text = (t < n_text);
    const int kbase = is_text ? t * TK : (t - n_text) * TK;
    const float* ksrc = is_text ? ktxt : khd;
    const float* vsrc = is_text ? vtxt : vhd;
    const int nrows = is_text ? NQ : K;
    __syncthreads();
    for (int i = tid; i < TK * DH; i += 256) {
      int r = i >> 7, d = i & (DH - 1);
      size_t row = (size_t)b * nrows + kbase + r;
      Ks[r][d] = ksrc[row * C + h * DH + d];
      Vs[r][d] = vsrc[row * C + h * DH + d];
    }
    __syncthreads();
    {  // scores: each thread 4 elements of S[32][32]
      const int r = tid >> 3;
      const int j0 = (tid & 7) * 4;
      float sj[4] = {0.f, 0.f, 0.f, 0.f};
      for (int d = 0; d < DH; ++d) {
        float qd = Qs[r][d];
#pragma unroll
        for (int j = 0; j < 4; ++j) sj[j] += qd * Ks[j0 + j][d];
      }
#pragma unroll
      for (int j = 0; j < 4; ++j) {
        float v = sj[j] * scale;
        if (is_text && (kbase + j0 + j) > (q0 + r)) v = -1e9f;
        Ss[r][j0 + j] = v;
      }
    }
    __syncthreads();
    if (tid < TQ) {  // online-softmax row update
      const int r = tid;
      float mx = row_m[r];
      for (int j = 0; j < TK; ++j) mx = fmaxf(mx, Ss[r][j]);
      float f = expf(row_m[r] - mx);
      float l = row_l[r] * f;
      for (int j = 0; j < TK; ++j) {
        float pv = expf(Ss[r][j] - mx);
        Ss[r][j] = pv;
        l += pv;
      }
      row_m[r] = mx; row_l[r] = l; row_f[r] = f;
    }
    __syncthreads();
    {  // O += P @ V, rescaled
      const float f = row_f[my_r];
#pragma unroll
      for (int dd = 0; dd < 16; ++dd) acc[dd] *= f;
      for (int j = 0; j < TK; ++j) {
        const float pv = Ss[my_r][j];
#pragma unroll
        for (int dd = 0; dd < 16; ++dd) acc[dd] += pv * Vs[j][my_d0 + dd];
      }
    }
  }
  const float invl = 1.f / row_l[my_r];
#pragma unroll
  for (int dd = 0; dd < 16; ++dd)
    outp[((size_t)b * NQ + q0 + my_r) * C + h * DH + my_d0 + dd] =
        acc[dd] * invl;
}

// ---------------------------------------------------------------------------
extern "C" void kernel_launch(void* const* d_in, const int* in_sizes, int n_in,
                              void* d_out, int out_size, void* d_ws,
                              size_t ws_size, hipStream_t stream) {
  const float* hs = (const float*)d_in[0];
  const float* img = (const float*)d_in[1];
  const float* wq = (const float*)d_in[2];
  const float* wk = (const float*)d_in[3];
  const float* wv = (const float*)d_in[4];
  const float* wo = (const float*)d_in[5];
  const float* cdw = (const float*)d_in[6];
  const float* ln1w = (const float*)d_in[7];
  const float* ln1b = (const float*)d_in[8];
  const float* plrw = (const float*)d_in[9];
  const float* piw = (const float*)d_in[10];
  const float* pib = (const float*)d_in[11];
  const float* ln2w = (const float*)d_in[12];
  const float* ln2b = (const float*)d_in[13];
  const float* offw = (const float*)d_in[14];
  const float* khw = (const float*)d_in[15];
  const float* khb = (const float*)d_in[16];
  const float* vhw = (const float*)d_in[17];
  const float* vhb = (const float*)d_in[18];
  float* outp = (float*)d_out;

  float* ws = (float*)d_ws;
  const size_t BNQC = (size_t)B * NQ * C;        // 4194304
  const size_t BKC = (size_t)B * K * C;          // 2359296
  const size_t NCK = (size_t)(B * G) * CD * K;   // 2359296
  float* qb = ws;
  float* ktb = qb + BNQC;
  float* vtb = ktb + BNQC;
  float* aob = vtb + BNQC;
  float* khd = aob + BNQC;
  float* vhd = khd + BKC;
  float* lrb = vhd + BKC;
  float* x1b = lrb + NCK;
  float* x2b = x1b + NCK;
  float* poolb = x2b + (size_t)(B * G) * INTER * K;
  float* gb = poolb + (size_t)(B * G) * CD;
  float* posb = gb + (size_t)(B * G) * INTER;
  float* sampb = lrb;  // lr buffer is dead before sampling starts

  dim3 blk(256);
  // 1. q/k/v projections
  gemm_nt<<<dim3(C / TS, (B * NQ) / TS), blk, 0, stream>>>(hs, wq, nullptr, qb,
                                                           B * NQ, C, C);
  gemm_nt<<<dim3(C / TS, (B * NQ) / TS), blk, 0, stream>>>(hs, wk, nullptr, ktb,
                                                           B * NQ, C, C);
  gemm_nt<<<dim3(C / TS, (B * NQ) / TS), blk, 0, stream>>>(hs, wv, nullptr, vtb,
                                                           B * NQ, C, C);
  // 2. offset network
  build_lr<<<dim3((B * G * CD * K) / 256), blk, 0, stream>>>(hs, lrb);
  pool_lr<<<dim3((B * G * CD + 255) / 256), blk, 0, stream>>>(lrb, poolb);
  dwconv_silu<<<dim3((B * G * CD * K) / 256), blk, 0, stream>>>(lrb, cdw, x1b);
  ln_c512<<<dim3(B * G * K), blk, 0, stream>>>(x1b, ln1w, ln1b);
  proj64<<<dim3(B * G * INTER), dim3(K), 0, stream>>>(x1b, plrw, x2b);
  gate_k<<<dim3((B * G * INTER + 63) / 64), dim3(64), 0, stream>>>(poolb, piw,
                                                                   pib, gb);
  ln2_off_pos<<<dim3((B * G * K) / 4), blk, 0, stream>>>(x2b, gb, ln2w, ln2b,
                                                         offw, posb);
  // 3. deformable gather
  sample_k<<<dim3(B * K), blk, 0, stream>>>(img, posb, sampb);
  // 4. HD k/v projections
  gemm_nt<<<dim3(C / TS, (B * K) / TS), blk, 0, stream>>>(sampb, khw, khb, khd,
                                                          B * K, C, C);
  gemm_nt<<<dim3(C / TS, (B * K) / TS), blk, 0, stream>>>(sampb, vhw, vhb, vhd,
                                                          B * K, C, C);
  // 5. attention
  attn_k<<<dim3(NQ / TQ, H, B), blk, 0, stream>>>(qb, ktb, vtb, khd, vhd, aob);
  // 6. output projection
  gemm_nt<<<dim3(C / TS, (B * NQ) / TS), blk, 0, stream>>>(aob, wo, nullptr,
                                                           outp, B * NQ, C, C);
}

// Round 2
// 478.973 us; speedup vs baseline: 8.8067x; 8.8067x over previous
//
#include <hip/hip_runtime.h>

typedef unsigned short u16;
typedef unsigned int u32;
typedef __attribute__((ext_vector_type(8))) short bf8;
typedef __attribute__((ext_vector_type(4))) float f4;
typedef __attribute__((ext_vector_type(4))) unsigned short us4;

constexpr int B = 2;
constexpr int NQ = 1024;
constexpr int C = 2048;
constexpr int DH = 128;
constexpr int G = 4;
constexpr int CD = 512;
constexpr int LR = 24;
constexpr int HR = 72;
constexpr int INTER = 64;
constexpr int K = LR * LR;  // 576
constexpr int NKV = NQ + K; // 1600

#define MFMA16(a, b, c) __builtin_amdgcn_mfma_f32_16x16x32_bf16(a, b, c, 0, 0, 0)
#define GLDS(g, l)                                                         \
  __builtin_amdgcn_global_load_lds(                                        \
      (const __attribute__((address_space(1))) void*)(g),                  \
      (__attribute__((address_space(3))) void*)(l), 16, 0, 0)

__device__ __forceinline__ u16 f2bf1(float f) {
  u32 u = __float_as_uint(f);
  u32 r = (u + 0x7fffu + ((u >> 16) & 1u)) >> 16;
  return (u16)r;
}

// ------------------------------ fp32 -> bf16 --------------------------------
__global__ __launch_bounds__(256) void f2bf_k(const float* __restrict__ in,
                                              u16* __restrict__ out, int n4) {
  int i = blockIdx.x * 256 + threadIdx.x;
  if (i >= n4) return;
  float4 v = ((const float4*)in)[i];
  us4 o;
  o.x = f2bf1(v.x); o.y = f2bf1(v.y); o.z = f2bf1(v.z); o.w = f2bf1(v.w);
  ((us4*)out)[i] = o;
}

// -------------------------- bf16 MFMA GEMM (m97) ----------------------------
// C[m][n] = sum_k A[m][k] * W[n][k]  (NT). 128x128 tile, BK=32, 4 waves 2x2.
// MODE 0: A=hs_bf [2048][2048], W in {wq,wk,wv} by nb/16; writes qb / Kg / Vg.
// MODE 1: A=samp_bf [1152][2048], W in {khw,vhw}; +bias; writes Kg/Vg @kv>=1024.
// MODE 2: A=aob_bf [2048][2048], W=wo; writes fp32 out.
template <int MODE>
__global__ __launch_bounds__(256) void gemm_mf(
    const u16* __restrict__ A, const u16* __restrict__ W0,
    const u16* __restrict__ W1, const u16* __restrict__ W2,
    const float* __restrict__ bias0, const float* __restrict__ bias1,
    u16* __restrict__ outq, u16* __restrict__ kg, u16* __restrict__ vg,
    float* __restrict__ outf) {
  __shared__ u16 As[128 * 32];
  __shared__ u16 Ws[128 * 32];
  const int tid = threadIdx.x, lane = tid & 63, w = tid >> 6;
  const int wr = w >> 1, wc = w & 1;
  const int m0 = blockIdx.y * 128, nb = blockIdx.x;
  const u16* Wp;
  if (MODE == 0) Wp = (nb < 16) ? W0 : (nb < 32) ? W1 : W2;
  else if (MODE == 1) Wp = (nb < 16) ? W0 : W1;
  else Wp = W0;
  const int n0l = (MODE == 2 ? nb : (nb & 15)) * 128;
  f4 acc[4][4];
#pragma unroll
  for (int i = 0; i < 4; ++i)
#pragma unroll
    for (int j = 0; j < 4; ++j) acc[i][j] = f4{0.f, 0.f, 0.f, 0.f};
  const int srow = lane >> 2, scol = (lane & 3) * 8;
  const int ch0 = w * 2;
  const u16* Ab = A + (size_t)m0 * 2048 + scol;
  const u16* Wb = Wp + (size_t)n0l * 2048 + scol;
  const int koff = (lane >> 4) * 8;
  const int arow = wr * 64 + (lane & 15), brow = wc * 64 + (lane & 15);
  for (int k0 = 0; k0 < 2048; k0 += 32) {
#pragma unroll
    for (int c = 0; c < 2; ++c) {
      const int chunk = ch0 + c;
      const int row = chunk * 16 + srow;
      GLDS(Ab + (size_t)row * 2048 + k0, As + chunk * 512 + lane * 8);
      GLDS(Wb + (size_t)row * 2048 + k0, Ws + chunk * 512 + lane * 8);
    }
    __syncthreads();
    bf8 af[4], bw[4];
#pragma unroll
    for (int i = 0; i < 4; ++i)
      af[i] = *(const bf8*)(As + (arow + i * 16) * 32 + koff);
#pragma unroll
    for (int j = 0; j < 4; ++j)
      bw[j] = *(const bf8*)(Ws + (brow + j * 16) * 32 + koff);
#pragma unroll
    for (int i = 0; i < 4; ++i)
#pragma unroll
      for (int j = 0; j < 4; ++j)
        acc[i][j] = MFMA16(af[i], bw[j], acc[i][j]);
    __syncthreads();
  }
  // epilogue
  const int rbase = (lane >> 4) * 4;
  const int cql = lane & 15;
#pragma unroll
  for (int i = 0; i < 4; ++i) {
#pragma unroll
    for (int j = 0; j < 4; ++j) {
      const int n = nb * 128 + wc * 64 + j * 16 + cql;
#pragma unroll
      for (int r = 0; r < 4; ++r) {
        const int m = m0 + wr * 64 + i * 16 + rbase + r;
        float v = acc[i][j][r];
        if (MODE == 0) {
          const int sel = n >> 11, nn = n & 2047, hh = nn >> 7, dd = nn & 127;
          const int bb = m >> 10, qq = m & 1023;
          const u16 bv = f2bf1(v);
          if (sel == 0) {
            outq[(size_t)m * 2048 + nn] = bv;
          } else if (sel == 1) {
            kg[(((size_t)(bb * 16 + hh) * 50 + (qq >> 5)) * 16 + (dd >> 3)) * 256 +
               (qq & 31) * 8 + (dd & 7)] = bv;
          } else {
            vg[((size_t)(bb * 16 + hh) * 200 + (qq >> 3)) * 1024 + dd * 8 +
               (qq & 7)] = bv;
          }
        } else if (MODE == 1) {
          const int sel = n >> 11, nn = n & 2047, hh = nn >> 7, dd = nn & 127;
          const int bb = m / 576;
          const int kv = 1024 + (m - bb * 576);
          v += (sel == 0) ? bias0[nn] : bias1[nn];
          const u16 bv = f2bf1(v);
          if (sel == 0) {
            kg[(((size_t)(bb * 16 + hh) * 50 + (kv >> 5)) * 16 + (dd >> 3)) * 256 +
               (kv & 31) * 8 + (dd & 7)] = bv;
          } else {
            vg[((size_t)(bb * 16 + hh) * 200 + (kv >> 3)) * 1024 + dd * 8 +
               (kv & 7)] = bv;
          }
        } else {
          outf[(size_t)m * 2048 + n] = v;
        }
      }
    }
  }
}

// ----------------------- offset network (tiny kernels) ----------------------
__global__ __launch_bounds__(256) void build_lr(const float* __restrict__ hs,
                                                float* __restrict__ lr) {
  int idx = blockIdx.x * 256 + threadIdx.x;
  if (idx >= B * G * CD * K) return;
  int p = idx % K;
  int c = (idx / K) % CD;
  int n = idx / (K * CD);
  int b = n >> 2, g = n & 3;
  lr[idx] = hs[((size_t)b * NQ + p) * C + g * CD + c];
}

__global__ __launch_bounds__(256) void pool_lr(const float* __restrict__ lr,
                                               float* __restrict__ pooled) {
  int row = (blockIdx.x * 256 + threadIdx.x) >> 6;
  int lane = threadIdx.x & 63;
  if (row >= B * G * CD) return;
  const float* p = lr + (size_t)row * K;
  float s = 0.f;
  for (int i = lane; i < K; i += 64) s += p[i];
  for (int o = 32; o; o >>= 1) s += __shfl_xor(s, o);
  if (lane == 0) pooled[row] = s * (1.f / K);
}

__global__ __launch_bounds__(256) void dwconv_silu(const float* __restrict__ lr,
                                                   const float* __restrict__ w,
                                                   float* __restrict__ x1) {
  int idx = blockIdx.x * 256 + threadIdx.x;
  if (idx >= B * G * CD * K) return;
  int p = idx % K;
  int c = (idx / K) % CD;
  int n = idx / (K * CD);
  int y = p / LR, x = p % LR;
  const float* wp = w + c * 9;
  const float* src = lr + ((size_t)n * CD + c) * K;
  float s = 0.f;
#pragma unroll
  for (int dy = -1; dy <= 1; ++dy)
#pragma unroll
    for (int dx = -1; dx <= 1; ++dx) {
      int yy = y + dy, xx = x + dx;
      if (yy < 0 || yy >= LR || xx < 0 || xx >= LR) continue;
      s += src[yy * LR + xx] * wp[(dy + 1) * 3 + dx + 1];
    }
  x1[idx] = s / (1.f + expf(-s));
}

// channel LN over 512, in-place; block per n, thread per pixel (coalesced).
__global__ __launch_bounds__(576) void ln_c512(float* __restrict__ x,
                                               const float* __restrict__ w,
                                               const float* __restrict__ b) {
  const int n = blockIdx.x;
  const int p = threadIdx.x;
  float* base = x + (size_t)n * CD * K + p;
  float s = 0.f, ss = 0.f;
  for (int c = 0; c < CD; ++c) {
    float v = base[(size_t)c * K];
    s += v; ss += v * v;
  }
  const float mean = s * (1.f / CD);
  const float inv = rsqrtf(ss * (1.f / CD) - mean * mean + 1e-5f);
  for (int c = 0; c < CD; ++c) {
    float v = base[(size_t)c * K];
    base[(size_t)c * K] = (v - mean) * inv * w[c] + b[c];
  }
}

__global__ __launch_bounds__(576) void proj64(const float* __restrict__ x1,
                                              const float* __restrict__ w,
                                              float* __restrict__ x2) {
  const int n = blockIdx.x >> 6;
  const int o = blockIdx.x & 63;
  const int p = threadIdx.x;
  const float* xb = x1 + (size_t)n * CD * K + p;
  const float* wb = w + o * CD;
  float s = 0.f;
  for (int c = 0; c < CD; ++c) s += xb[(size_t)c * K] * wb[c];
  x2[((size_t)n * INTER + o) * K + p] = s;
}

__global__ __launch_bounds__(64) void gate_k(const float* __restrict__ pooled,
                                             const float* __restrict__ w,
                                             const float* __restrict__ bias,
                                             float* __restrict__ gate) {
  int idx = blockIdx.x * 64 + threadIdx.x;
  if (idx >= B * G * INTER) return;
  int n = idx >> 6, o = idx & 63;
  const float* pb = pooled + n * CD;
  const float* wb = w + o * CD;
  float s = bias[o];
  for (int c = 0; c < CD; ++c) s += pb[c] * wb[c];
  gate[idx] = 1.f / (1.f + expf(-s));
}

__global__ __launch_bounds__(256) void ln2_off_pos(
    const float* __restrict__ x2, const float* __restrict__ gate,
    const float* __restrict__ ln2w, const float* __restrict__ ln2b,
    const float* __restrict__ offw, float* __restrict__ pos) {
  int wid = (blockIdx.x * 256 + threadIdx.x) >> 6;
  int lane = threadIdx.x & 63;
  if (wid >= B * G * K) return;
  int n = wid / K, p = wid % K;
  float v = x2[((size_t)n * INTER + lane) * K + p] * gate[n * INTER + lane];
  float s = v, ss = v * v;
  for (int o = 32; o; o >>= 1) {
    s += __shfl_xor(s, o);
    ss += __shfl_xor(ss, o);
  }
  float mean = s * (1.f / INTER);
  float var = ss * (1.f / INTER) - mean * mean;
  float xn = (v - mean) * rsqrtf(var + 1e-5f) * ln2w[lane] + ln2b[lane];
  float ox = xn * offw[lane];
  float oy = xn * offw[INTER + lane];
  for (int o = 32; o; o >>= 1) {
    ox += __shfl_xor(ox, o);
    oy += __shfl_xor(oy, o);
  }
  if (lane == 0) {
    int yi = p / LR, xi = p % LR;
    float rx = (xi + 0.5f) / 23.f * 2.f - 1.f;
    float ry = (yi + 0.5f) / 23.f * 2.f - 1.f;
    pos[((size_t)n * K + p) * 2 + 0] = tanhf(rx + ox);
    pos[((size_t)n * K + p) * 2 + 1] = tanhf(ry + oy);
  }
}

// bilinear sample -> bf16 samp [B*K][C]
__global__ __launch_bounds__(256) void sample_k(const float* __restrict__ img,
                                                const float* __restrict__ pos,
                                                u16* __restrict__ samp) {
  const int bk = blockIdx.x;
  const int b = bk / K, k = bk % K;
  __shared__ int s_idx[G][4];
  __shared__ float s_w[G][4];
  if (threadIdx.x < G) {
    int g = threadIdx.x;
    int n = b * G + g;
    float px = pos[((size_t)n * K + k) * 2 + 0];
    float py = pos[((size_t)n * K + k) * 2 + 1];
    float x = (px + 1.f) * 0.5f * (HR - 1);
    float y = (py + 1.f) * 0.5f * (HR - 1);
    float x0f = floorf(x), y0f = floorf(y);
    float wx = x - x0f, wy = y - y0f;
    int x0 = min(max((int)x0f, 0), HR - 1);
    int x1 = min(x0 + 1, HR - 1);
    int y0 = min(max((int)y0f, 0), HR - 1);
    int y1 = min(y0 + 1, HR - 1);
    s_idx[g][0] = y0 * HR + x0;
    s_idx[g][1] = y0 * HR + x1;
    s_idx[g][2] = y1 * HR + x0;
    s_idx[g][3] = y1 * HR + x1;
    s_w[g][0] = (1.f - wx) * (1.f - wy);
    s_w[g][1] = wx * (1.f - wy);
    s_w[g][2] = (1.f - wx) * wy;
    s_w[g][3] = wx * wy;
  }
  __syncthreads();
  const float* ib = img + (size_t)b * HR * HR * C;
  u16* ob = samp + ((size_t)b * K + k) * C;
  for (int ch = threadIdx.x; ch < C; ch += 256) {
    int g = ch >> 9;
    float v = s_w[g][0] * ib[(size_t)s_idx[g][0] * C + ch] +
              s_w[g][1] * ib[(size_t)s_idx[g][1] * C + ch] +
              s_w[g][2] * ib[(size_t)s_idx[g][2] * C + ch] +
              s_w[g][3] * ib[(size_t)s_idx[g][3] * C + ch];
    ob[ch] = f2bf1(v);
  }
}

// --------------------------- MFMA flash attention ---------------------------
// 4 waves/block, wave = 16 q rows; KV tile 32. Kg subtiled [dblk][kv][8],
// Vg subtiled [kvblk][d][8] -> 2-way-bank ds_read_b128 everywhere.
__global__ __launch_bounds__(256) void attn_mfma(
    const u16* __restrict__ qb, const u16* __restrict__ kg,
    const u16* __restrict__ vg, u16* __restrict__ aob) {
  const int bh = blockIdx.y, b = bh >> 4, h = bh & 15;
  const int q0 = blockIdx.x * 64;
  const int tid = threadIdx.x, lane = tid & 63, w = tid >> 6;
  const int qw = q0 + w * 16;
  const int col = lane & 15, kpart = lane >> 4, rbase = kpart * 4;
  __shared__ u16 Ks[4096];        // 8KB: [dblk16][kv32][8]
  __shared__ u16 Vs[4096];        // 8KB: [kvblk4][d128][8]
  __shared__ u16 Pl[4][16 * 72];  // P per wave, row stride 72 (2-way banks)
  bf8 qf[4];
  {
    const u16* qp = qb + (size_t)(b * 1024 + qw + col) * 2048 + h * 128 + kpart * 8;
#pragma unroll
    for (int dc = 0; dc < 4; ++dc) qf[dc] = *(const bf8*)(qp + dc * 32);
  }
  f4 o[8];
#pragma unroll
  for (int df = 0; df < 8; ++df) o[df] = f4{0.f, 0.f, 0.f, 0.f};
  float m_r[4] = {-1e30f, -1e30f, -1e30f, -1e30f};
  float l_r[4] = {0.f, 0.f, 0.f, 0.f};
  const float scale = 0.08838834764831845f;
  const int nt_text = (q0 + 64) >> 5;
  const int n_tiles = nt_text + 18;
  const u16* kbh = kg + (size_t)bh * (NKV * 128);
  const u16* vbh = vg + (size_t)bh * (NKV * 128);
  u16* pw = &Pl[w][0];
  for (int t = 0; t < n_tiles; ++t) {
    const bool is_text = t < nt_text;
    const int kv0 = is_text ? (t << 5) : (1024 + ((t - nt_text) << 5));
    __syncthreads();
    {
      const u16* gk = kbh + (size_t)(kv0 >> 5) * 4096 + w * 1024 + lane * 8;
      GLDS(gk, Ks + w * 1024 + lane * 8);
      GLDS(gk + 512, Ks + w * 1024 + 512 + lane * 8);
      const u16* gv = vbh + (size_t)(kv0 >> 3) * 1024 + w * 1024 + lane * 8;
      GLDS(gv, Vs + w * 1024 + lane * 8);
      GLDS(gv + 512, Vs + w * 1024 + 512 + lane * 8);
    }
    __syncthreads();
    f4 s0 = {0.f, 0.f, 0.f, 0.f}, s1 = {0.f, 0.f, 0.f, 0.f};
#pragma unroll
    for (int dc = 0; dc < 4; ++dc) {
      const int dblk = dc * 4 + kpart;
      bf8 k0f = *(const bf8*)(Ks + (dblk * 32 + col) * 8);
      bf8 k1f = *(const bf8*)(Ks + (dblk * 32 + 16 + col) * 8);
      s0 = MFMA16(qf[dc], k0f, s0);
      s1 = MFMA16(qf[dc], k1f, s1);
    }
    float p0[4], p1[4], fr[4];
#pragma unroll
    for (int r = 0; r < 4; ++r) {
      float a = s0[r] * scale, c2 = s1[r] * scale;
      if (is_text) {
        const int qg = qw + rbase + r;
        if (kv0 + col > qg) a = -1e30f;
        if (kv0 + 16 + col > qg) c2 = -1e30f;
      }
      float mx = fmaxf(a, c2);
      mx = fmaxf(mx, __shfl_xor(mx, 1));
      mx = fmaxf(mx, __shfl_xor(mx, 2));
      mx = fmaxf(mx, __shfl_xor(mx, 4));
      mx = fmaxf(mx, __shfl_xor(mx, 8));
      const float mn = fmaxf(m_r[r], mx);
      const float f = __expf(m_r[r] - mn);
      m_r[r] = mn;
      p0[r] = __expf(a - mn);
      p1[r] = __expf(c2 - mn);
      float ps = p0[r] + p1[r];
      ps += __shfl_xor(ps, 1);
      ps += __shfl_xor(ps, 2);
      ps += __shfl_xor(ps, 4);
      ps += __shfl_xor(ps, 8);
      l_r[r] = l_r[r] * f + ps;
      fr[r] = f;
    }
#pragma unroll
    for (int df = 0; df < 8; ++df) {
      o[df][0] *= fr[0]; o[df][1] *= fr[1];
      o[df][2] *= fr[2]; o[df][3] *= fr[3];
    }
#pragma unroll
    for (int r = 0; r < 4; ++r) {
      pw[(rbase + r) * 72 + col] = f2bf1(p0[r]);
      pw[(rbase + r) * 72 + 16 + col] = f2bf1(p1[r]);
    }
    bf8 pa = *(const bf8*)(pw + col * 72 + kpart * 8);
#pragma unroll
    for (int df = 0; df < 8; ++df) {
      bf8 vf = *(const bf8*)(Vs + (kpart * 128 + df * 16 + col) * 8);
      o[df] = MFMA16(pa, vf, o[df]);
    }
  }
  float inv[4];
#pragma unroll
  for (int r = 0; r < 4; ++r) inv[r] = 1.f / l_r[r];
  u16* ob = aob + (size_t)(b * 1024 + qw + rbase) * 2048 + h * 128 + col;
#pragma unroll
  for (int df = 0; df < 8; ++df)
#pragma unroll
    for (int r = 0; r < 4; ++r)
      ob[(size_t)r * 2048 + df * 16] = f2bf1(o[df][r] * inv[r]);
}

// ---------------------------------------------------------------------------
extern "C" void kernel_launch(void* const* d_in, const int* in_sizes, int n_in,
                              void* d_out, int out_size, void* d_ws,
                              size_t ws_size, hipStream_t stream) {
  const float* hs = (const float*)d_in[0];
  const float* img = (const float*)d_in[1];
  const float* wq = (const float*)d_in[2];
  const float* wk = (const float*)d_in[3];
  const float* wv = (const float*)d_in[4];
  const float* wo = (const float*)d_in[5];
  const float* cdw = (const float*)d_in[6];
  const float* ln1w = (const float*)d_in[7];
  const float* ln1b = (const float*)d_in[8];
  const float* plrw = (const float*)d_in[9];
  const float* piw = (const float*)d_in[10];
  const float* pib = (const float*)d_in[11];
  const float* ln2w = (const float*)d_in[12];
  const float* ln2b = (const float*)d_in[13];
  const float* offw = (const float*)d_in[14];
  const float* khw = (const float*)d_in[15];
  const float* khb = (const float*)d_in[16];
  const float* vhw = (const float*)d_in[17];
  const float* vhb = (const float*)d_in[18];
  float* outp = (float*)d_out;

  u16* wsp = (u16*)d_ws;
  const size_t SZ = 4194304;  // 2048*2048
  u16* hs_bf = wsp;
  u16* wq_bf = wsp + SZ;       // reused as aob_bf after gemm<0>
  u16* wk_bf = wsp + 2 * SZ;
  u16* wv_bf = wsp + 3 * SZ;
  u16* wo_bf = wsp + 4 * SZ;
  u16* khw_bf = wsp + 5 * SZ;
  u16* vhw_bf = wsp + 6 * SZ;
  u16* qb_bf = wsp + 7 * SZ;
  u16* samp_bf = wsp + 8 * SZ;             // 1152*2048 = 2359296
  u16* kg = wsp + 8 * SZ + 2359296;        // 2*16*1600*128 = 6553600
  u16* vg = kg + 6553600;
  // fp32 scratch overlaps kg/vg (dead before gemms run)
  float* f0 = (float*)kg;
  float* lrb = f0;
  float* x1b = lrb + 2359296;
  float* x2b = x1b + 2359296;
  float* poolb = x2b + 294912;
  float* gb = poolb + 4096;
  float* posb = (float*)(vg + 6553600);    // 9216 floats, after kg+vg
  u16* aob_bf = wq_bf;

  dim3 blk(256);
  // ---- offset network (fp32, uses scratch that later becomes kg/vg) ----
  build_lr<<<dim3((B * G * CD * K) / 256), blk, 0, stream>>>(hs, lrb);
  pool_lr<<<dim3((B * G * CD) / 4), blk, 0, stream>>>(lrb, poolb);
  dwconv_silu<<<dim3((B * G * CD * K) / 256), blk, 0, stream>>>(lrb, cdw, x1b);
  ln_c512<<<dim3(B * G), dim3(576), 0, stream>>>(x1b, ln1w, ln1b);
  proj64<<<dim3(B * G * INTER), dim3(576), 0, stream>>>(x1b, plrw, x2b);
  gate_k<<<dim3((B * G * INTER) / 64), dim3(64), 0, stream>>>(poolb, piw, pib, gb);
  ln2_off_pos<<<dim3((B * G * K) / 4), blk, 0, stream>>>(x2b, gb, ln2w, ln2b,
                                                         offw, posb);
  sample_k<<<dim3(B * K), blk, 0, stream>>>(img, posb, samp_bf);

  // ---- bf16 conversions ----
  const int n4 = SZ / 4;
  f2bf_k<<<dim3(n4 / 256), blk, 0, stream>>>(hs, hs_bf, n4);
  f2bf_k<<<dim3(n4 / 256), blk, 0, stream>>>(wq, wq_bf, n4);
  f2bf_k<<<dim3(n4 / 256), blk, 0, stream>>>(wk, wk_bf, n4);
  f2bf_k<<<dim3(n4 / 256), blk, 0, stream>>>(wv, wv_bf, n4);
  f2bf_k<<<dim3(n4 / 256), blk, 0, stream>>>(wo, wo_bf, n4);
  f2bf_k<<<dim3(n4 / 256), blk, 0, stream>>>(khw, khw_bf, n4);
  f2bf_k<<<dim3(n4 / 256), blk, 0, stream>>>(vhw, vhw_bf, n4);

  // ---- MFMA GEMMs ----
  gemm_mf<0><<<dim3(48, 16), blk, 0, stream>>>(hs_bf, wq_bf, wk_bf, wv_bf,
                                               nullptr, nullptr, qb_bf, kg, vg,
                                               nullptr);
  gemm_mf<1><<<dim3(32, 9), blk, 0, stream>>>(samp_bf, khw_bf, vhw_bf, nullptr,
                                              khb, vhb, nullptr, kg, vg,
                                              nullptr);
  // ---- attention ----
  attn_mfma<<<dim3(16, 32), blk, 0, stream>>>(qb_bf, kg, vg, aob_bf);
  // ---- output projection ----
  gemm_mf<2><<<dim3(16, 16), blk, 0, stream>>>(aob_bf, wo_bf, nullptr, nullptr,
                                               nullptr, nullptr, nullptr,
                                               nullptr, nullptr, outp);
}

// Round 3
// 438.824 us; speedup vs baseline: 9.6124x; 1.0915x over previous
//
#include <hip/hip_runtime.h>

typedef unsigned short u16;
typedef unsigned int u32;
typedef __attribute__((ext_vector_type(8))) short bf8;
typedef __attribute__((ext_vector_type(4))) float f4;
typedef __attribute__((ext_vector_type(4))) unsigned short us4;

constexpr int B = 2;
constexpr int NQ = 1024;
constexpr int C = 2048;
constexpr int DH = 128;
constexpr int G = 4;
constexpr int CD = 512;
constexpr int LR = 24;
constexpr int HR = 72;
constexpr int INTER = 64;
constexpr int K = LR * LR;  // 576
constexpr int NKV = NQ + K; // 1600

#define MFMA16(a, b, c) __builtin_amdgcn_mfma_f32_16x16x32_bf16(a, b, c, 0, 0, 0)
#define GLDS(g, l)                                                         \
  __builtin_amdgcn_global_load_lds(                                        \
      (const __attribute__((address_space(1))) void*)(g),                  \
      (__attribute__((address_space(3))) void*)(l), 16, 0, 0)

__device__ __forceinline__ u16 f2bf1(float f) {
  u32 u = __float_as_uint(f);
  u32 r = (u + 0x7fffu + ((u >> 16) & 1u)) >> 16;
  return (u16)r;
}

// --------------------- fused fp32 -> bf16 (7 tensors) -----------------------
__global__ __launch_bounds__(256) void f2bf_k7(
    const float* __restrict__ s0, const float* __restrict__ s1,
    const float* __restrict__ s2, const float* __restrict__ s3,
    const float* __restrict__ s4, const float* __restrict__ s5,
    const float* __restrict__ s6, u16* __restrict__ d0, u16* __restrict__ d1,
    u16* __restrict__ d2, u16* __restrict__ d3, u16* __restrict__ d4,
    u16* __restrict__ d5, u16* __restrict__ d6) {
  const float* s;
  u16* d;
  switch (blockIdx.y) {
    case 0: s = s0; d = d0; break;
    case 1: s = s1; d = d1; break;
    case 2: s = s2; d = d2; break;
    case 3: s = s3; d = d3; break;
    case 4: s = s4; d = d4; break;
    case 5: s = s5; d = d5; break;
    default: s = s6; d = d6; break;
  }
  int i = blockIdx.x * 256 + threadIdx.x;
  float4 v = ((const float4*)s)[i];
  us4 o;
  o.x = f2bf1(v.x); o.y = f2bf1(v.y); o.z = f2bf1(v.z); o.w = f2bf1(v.w);
  ((us4*)d)[i] = o;
}

// ----------------- bf16 MFMA GEMM (m97 + 2-phase dbuf) ----------------------
// C[m][n] = sum_k A[m][k] * W[n][k]  (NT). 128x128 tile, BK=32, 4 waves 2x2.
template <int MODE>
__global__ __launch_bounds__(256) void gemm_mf(
    const u16* __restrict__ A, const u16* __restrict__ W0,
    const u16* __restrict__ W1, const u16* __restrict__ W2,
    const float* __restrict__ bias0, const float* __restrict__ bias1,
    u16* __restrict__ outq, u16* __restrict__ kg, u16* __restrict__ vg,
    float* __restrict__ outf) {
  __shared__ u16 As[2][4096];
  __shared__ u16 Ws[2][4096];
  const int tid = threadIdx.x, lane = tid & 63, w = tid >> 6;
  const int wr = w >> 1, wc = w & 1;
  const int m0 = blockIdx.y * 128, nb = blockIdx.x;
  const u16* Wp;
  if (MODE == 0) Wp = (nb < 16) ? W0 : (nb < 32) ? W1 : W2;
  else if (MODE == 1) Wp = (nb < 16) ? W0 : W1;
  else Wp = W0;
  const int n0l = (MODE == 2 ? nb : (nb & 15)) * 128;
  f4 acc[4][4];
#pragma unroll
  for (int i = 0; i < 4; ++i)
#pragma unroll
    for (int j = 0; j < 4; ++j) acc[i][j] = f4{0.f, 0.f, 0.f, 0.f};
  const int srow = lane >> 2, scol = (lane & 3) * 8;
  const int ch0 = w * 2;
  const u16* Ab = A + (size_t)m0 * 2048 + scol;
  const u16* Wb = Wp + (size_t)n0l * 2048 + scol;
  const int koff = (lane >> 4) * 8;
  const int arow = wr * 64 + (lane & 15), brow = wc * 64 + (lane & 15);

#define GSTAGE(bi, k0)                                                      \
  do {                                                                      \
    _Pragma("unroll") for (int c = 0; c < 2; ++c) {                         \
      const int chunk = ch0 + c;                                            \
      const int row = chunk * 16 + srow;                                    \
      GLDS(Ab + (size_t)row * 2048 + (k0), &As[bi][chunk * 512 + lane * 8]);\
      GLDS(Wb + (size_t)row * 2048 + (k0), &Ws[bi][chunk * 512 + lane * 8]);\
    }                                                                       \
  } while (0)

  GSTAGE(0, 0);
  int cur = 0;
  for (int k0 = 0; k0 < 2048; k0 += 32) {
    __syncthreads();  // drains stage(cur); prev compute done reading cur^1
    if (k0 + 32 < 2048) GSTAGE(cur ^ 1, k0 + 32);
    bf8 af[4], bw[4];
#pragma unroll
    for (int i = 0; i < 4; ++i)
      af[i] = *(const bf8*)(&As[cur][(arow + i * 16) * 32 + koff]);
#pragma unroll
    for (int j = 0; j < 4; ++j)
      bw[j] = *(const bf8*)(&Ws[cur][(brow + j * 16) * 32 + koff]);
#pragma unroll
    for (int i = 0; i < 4; ++i)
#pragma unroll
      for (int j = 0; j < 4; ++j)
        acc[i][j] = MFMA16(af[i], bw[j], acc[i][j]);
    cur ^= 1;
  }
#undef GSTAGE
  // epilogue
  const int rbase = (lane >> 4) * 4;
  const int cql = lane & 15;
#pragma unroll
  for (int i = 0; i < 4; ++i) {
#pragma unroll
    for (int j = 0; j < 4; ++j) {
      const int n = nb * 128 + wc * 64 + j * 16 + cql;
#pragma unroll
      for (int r = 0; r < 4; ++r) {
        const int m = m0 + wr * 64 + i * 16 + rbase + r;
        float v = acc[i][j][r];
        if (MODE == 0) {
          const int sel = n >> 11, nn = n & 2047, hh = nn >> 7, dd = nn & 127;
          const int bb = m >> 10, qq = m & 1023;
          const u16 bv = f2bf1(v);
          if (sel == 0) {
            outq[(size_t)m * 2048 + nn] = bv;
          } else if (sel == 1) {
            kg[(((size_t)(bb * 16 + hh) * 50 + (qq >> 5)) * 16 + (dd >> 3)) * 256 +
               (qq & 31) * 8 + (dd & 7)] = bv;
          } else {
            vg[((size_t)(bb * 16 + hh) * 200 + (qq >> 3)) * 1024 + dd * 8 +
               (qq & 7)] = bv;
          }
        } else if (MODE == 1) {
          const int sel = n >> 11, nn = n & 2047, hh = nn >> 7, dd = nn & 127;
          const int bb = m / 576;
          const int kv = 1024 + (m - bb * 576);
          v += (sel == 0) ? bias0[nn] : bias1[nn];
          const u16 bv = f2bf1(v);
          if (sel == 0) {
            kg[(((size_t)(bb * 16 + hh) * 50 + (kv >> 5)) * 16 + (dd >> 3)) * 256 +
               (kv & 31) * 8 + (dd & 7)] = bv;
          } else {
            vg[((size_t)(bb * 16 + hh) * 200 + (kv >> 3)) * 1024 + dd * 8 +
               (kv & 7)] = bv;
          }
        } else {
          outf[(size_t)m * 2048 + n] = v;
        }
      }
    }
  }
}

// ----------------------- offset network (tiny kernels) ----------------------
__global__ __launch_bounds__(256) void build_lr(const float* __restrict__ hs,
                                                float* __restrict__ lr) {
  int idx = blockIdx.x * 256 + threadIdx.x;
  if (idx >= B * G * CD * K) return;
  int p = idx % K;
  int c = (idx / K) % CD;
  int n = idx / (K * CD);
  int b = n >> 2, g = n & 3;
  lr[idx] = hs[((size_t)b * NQ + p) * C + g * CD + c];
}

__global__ __launch_bounds__(256) void pool_lr(const float* __restrict__ lr,
                                               float* __restrict__ pooled) {
  int row = (blockIdx.x * 256 + threadIdx.x) >> 6;
  int lane = threadIdx.x & 63;
  if (row >= B * G * CD) return;
  const float* p = lr + (size_t)row * K;
  float s = 0.f;
  for (int i = lane; i < K; i += 64) s += p[i];
  for (int o = 32; o; o >>= 1) s += __shfl_xor(s, o);
  if (lane == 0) pooled[row] = s * (1.f / K);
}

__global__ __launch_bounds__(256) void dwconv_silu(const float* __restrict__ lr,
                                                   const float* __restrict__ w,
                                                   float* __restrict__ x1) {
  int idx = blockIdx.x * 256 + threadIdx.x;
  if (idx >= B * G * CD * K) return;
  int p = idx % K;
  int c = (idx / K) % CD;
  int n = idx / (K * CD);
  int y = p / LR, x = p % LR;
  const float* wp = w + c * 9;
  const float* src = lr + ((size_t)n * CD + c) * K;
  float s = 0.f;
#pragma unroll
  for (int dy = -1; dy <= 1; ++dy)
#pragma unroll
    for (int dx = -1; dx <= 1; ++dx) {
      int yy = y + dy, xx = x + dx;
      if (yy < 0 || yy >= LR || xx < 0 || xx >= LR) continue;
      s += src[yy * LR + xx] * wp[(dy + 1) * 3 + dx + 1];
    }
  x1[idx] = s / (1.f + expf(-s));
}

// channel LN over 512. grid = (B*G)*9 blocks; block: 64 pixels x 4 c-groups.
__global__ __launch_bounds__(256) void ln_c512(float* __restrict__ x,
                                               const float* __restrict__ w,
                                               const float* __restrict__ b) {
  const int n = blockIdx.x / 9;
  const int p0 = (blockIdx.x % 9) * 64;
  const int pl = threadIdx.x & 63;
  const int cg = threadIdx.x >> 6;
  float* base = x + (size_t)n * CD * K + p0 + pl;
  float s = 0.f, ss = 0.f;
  for (int c = cg * 128; c < cg * 128 + 128; ++c) {
    float v = base[(size_t)c * K];
    s += v; ss += v * v;
  }
  __shared__ float rs[4][64], rss[4][64];
  rs[cg][pl] = s; rss[cg][pl] = ss;
  __syncthreads();
  float S = rs[0][pl] + rs[1][pl] + rs[2][pl] + rs[3][pl];
  float SS = rss[0][pl] + rss[1][pl] + rss[2][pl] + rss[3][pl];
  const float mean = S * (1.f / CD);
  const float inv = rsqrtf(SS * (1.f / CD) - mean * mean + 1e-5f);
  for (int c = cg * 128; c < cg * 128 + 128; ++c) {
    float v = base[(size_t)c * K];
    base[(size_t)c * K] = (v - mean) * inv * w[c] + b[c];
  }
}

// x2[n][o][p] = sum_c x1[n][c][p] * w[o][c]; 8 outputs per x1 read.
__global__ __launch_bounds__(576) void proj64(const float* __restrict__ x1,
                                              const float* __restrict__ w,
                                              float* __restrict__ x2) {
  const int n = blockIdx.x >> 3;
  const int o0 = (blockIdx.x & 7) * 8;
  const int p = threadIdx.x;
  const float* xb = x1 + (size_t)n * CD * K + p;
  float acc[8] = {0.f, 0.f, 0.f, 0.f, 0.f, 0.f, 0.f, 0.f};
  for (int c = 0; c < CD; ++c) {
    float v = xb[(size_t)c * K];
#pragma unroll
    for (int j = 0; j < 8; ++j) acc[j] += v * w[(o0 + j) * CD + c];
  }
#pragma unroll
  for (int j = 0; j < 8; ++j)
    x2[((size_t)n * INTER + o0 + j) * K + p] = acc[j];
}

__global__ __launch_bounds__(64) void gate_k(const float* __restrict__ pooled,
                                             const float* __restrict__ w,
                                             const float* __restrict__ bias,
                                             float* __restrict__ gate) {
  int idx = blockIdx.x * 64 + threadIdx.x;
  if (idx >= B * G * INTER) return;
  int n = idx >> 6, o = idx & 63;
  const float* pb = pooled + n * CD;
  const float* wb = w + o * CD;
  float s = bias[o];
  for (int c = 0; c < CD; ++c) s += pb[c] * wb[c];
  gate[idx] = 1.f / (1.f + expf(-s));
}

__global__ __launch_bounds__(256) void ln2_off_pos(
    const float* __restrict__ x2, const float* __restrict__ gate,
    const float* __restrict__ ln2w, const float* __restrict__ ln2b,
    const float* __restrict__ offw, float* __restrict__ pos) {
  int wid = (blockIdx.x * 256 + threadIdx.x) >> 6;
  int lane = threadIdx.x & 63;
  if (wid >= B * G * K) return;
  int n = wid / K, p = wid % K;
  float v = x2[((size_t)n * INTER + lane) * K + p] * gate[n * INTER + lane];
  float s = v, ss = v * v;
  for (int o = 32; o; o >>= 1) {
    s += __shfl_xor(s, o);
    ss += __shfl_xor(ss, o);
  }
  float mean = s * (1.f / INTER);
  float var = ss * (1.f / INTER) - mean * mean;
  float xn = (v - mean) * rsqrtf(var + 1e-5f) * ln2w[lane] + ln2b[lane];
  float ox = xn * offw[lane];
  float oy = xn * offw[INTER + lane];
  for (int o = 32; o; o >>= 1) {
    ox += __shfl_xor(ox, o);
    oy += __shfl_xor(oy, o);
  }
  if (lane == 0) {
    int yi = p / LR, xi = p % LR;
    float rx = (xi + 0.5f) / 23.f * 2.f - 1.f;
    float ry = (yi + 0.5f) / 23.f * 2.f - 1.f;
    pos[((size_t)n * K + p) * 2 + 0] = tanhf(rx + ox);
    pos[((size_t)n * K + p) * 2 + 1] = tanhf(ry + oy);
  }
}

__global__ __launch_bounds__(256) void sample_k(const float* __restrict__ img,
                                                const float* __restrict__ pos,
                                                u16* __restrict__ samp) {
  const int bk = blockIdx.x;
  const int b = bk / K, k = bk % K;
  __shared__ int s_idx[G][4];
  __shared__ float s_w[G][4];
  if (threadIdx.x < G) {
    int g = threadIdx.x;
    int n = b * G + g;
    float px = pos[((size_t)n * K + k) * 2 + 0];
    float py = pos[((size_t)n * K + k) * 2 + 1];
    float x = (px + 1.f) * 0.5f * (HR - 1);
    float y = (py + 1.f) * 0.5f * (HR - 1);
    float x0f = floorf(x), y0f = floorf(y);
    float wx = x - x0f, wy = y - y0f;
    int x0 = min(max((int)x0f, 0), HR - 1);
    int x1 = min(x0 + 1, HR - 1);
    int y0 = min(max((int)y0f, 0), HR - 1);
    int y1 = min(y0 + 1, HR - 1);
    s_idx[g][0] = y0 * HR + x0;
    s_idx[g][1] = y0 * HR + x1;
    s_idx[g][2] = y1 * HR + x0;
    s_idx[g][3] = y1 * HR + x1;
    s_w[g][0] = (1.f - wx) * (1.f - wy);
    s_w[g][1] = wx * (1.f - wy);
    s_w[g][2] = (1.f - wx) * wy;
    s_w[g][3] = wx * wy;
  }
  __syncthreads();
  const float* ib = img + (size_t)b * HR * HR * C;
  u16* ob = samp + ((size_t)b * K + k) * C;
  for (int ch = threadIdx.x; ch < C; ch += 256) {
    int g = ch >> 9;
    float v = s_w[g][0] * ib[(size_t)s_idx[g][0] * C + ch] +
              s_w[g][1] * ib[(size_t)s_idx[g][1] * C + ch] +
              s_w[g][2] * ib[(size_t)s_idx[g][2] * C + ch] +
              s_w[g][3] * ib[(size_t)s_idx[g][3] * C + ch];
    ob[ch] = f2bf1(v);
  }
}

// ------------------ MFMA flash attention (2-phase dbuf) ---------------------
__global__ __launch_bounds__(256) void attn_mfma(
    const u16* __restrict__ qb, const u16* __restrict__ kg,
    const u16* __restrict__ vg, u16* __restrict__ aob) {
  // balanced remap: blocks i and i+256 (same CU slot) get complementary work
  const int i = blockIdx.x;
  const int pair = i & 255, half = i >> 8;
  const int bh = pair & 31;
  const int q8 = pair >> 5;
  const int qblk = half ? (15 - q8) : q8;
  const int b = bh >> 4, h = bh & 15;
  const int q0 = qblk * 64;
  const int tid = threadIdx.x, lane = tid & 63, w = tid >> 6;
  const int qw = q0 + w * 16;
  const int col = lane & 15, kpart = lane >> 4, rbase = kpart * 4;
  __shared__ u16 Ks[2][4096];     // [dblk16][kv32][8]
  __shared__ u16 Vs[2][4096];     // [kvblk4][d128][8]
  __shared__ u16 Pl[4][16 * 72];  // P per wave, row stride 72
  bf8 qf[4];
  {
    const u16* qp =
        qb + (size_t)(b * 1024 + qw + col) * 2048 + h * 128 + kpart * 8;
#pragma unroll
    for (int dc = 0; dc < 4; ++dc) qf[dc] = *(const bf8*)(qp + dc * 32);
  }
  f4 o[8];
#pragma unroll
  for (int df = 0; df < 8; ++df) o[df] = f4{0.f, 0.f, 0.f, 0.f};
  float m_r[4] = {-1e30f, -1e30f, -1e30f, -1e30f};
  float l_r[4] = {0.f, 0.f, 0.f, 0.f};
  const float scale = 0.08838834764831845f;
  const int nt_text = (q0 + 64) >> 5;
  const int n_tiles = nt_text + 18;
  const u16* kbh = kg + (size_t)bh * (NKV * 128);
  const u16* vbh = vg + (size_t)bh * (NKV * 128);
  u16* pw = &Pl[w][0];

#define ASTAGE(bi, kv0)                                                     \
  do {                                                                      \
    const u16* gk = kbh + (size_t)((kv0) >> 5) * 4096 + w * 1024 + lane * 8;\
    GLDS(gk, &Ks[bi][w * 1024 + lane * 8]);                                 \
    GLDS(gk + 512, &Ks[bi][w * 1024 + 512 + lane * 8]);                     \
    const u16* gv = vbh + (size_t)((kv0) >> 3) * 1024 + w * 1024 + lane * 8;\
    GLDS(gv, &Vs[bi][w * 1024 + lane * 8]);                                 \
    GLDS(gv + 512, &Vs[bi][w * 1024 + 512 + lane * 8]);                     \
  } while (0)

  ASTAGE(0, 0);
  int cur = 0;
  for (int t = 0; t < n_tiles; ++t) {
    const bool is_text = t < nt_text;
    const int kv0 = is_text ? (t << 5) : (1024 + ((t - nt_text) << 5));
    __syncthreads();  // drains stage(cur); all waves done reading cur^1
    if (t + 1 < n_tiles) {
      const int t1 = t + 1;
      const int kv1 = (t1 < nt_text) ? (t1 << 5) : (1024 + ((t1 - nt_text) << 5));
      ASTAGE(cur ^ 1, kv1);
    }
    const u16* ksb = &Ks[cur][0];
    const u16* vsb = &Vs[cur][0];
    f4 s0 = {0.f, 0.f, 0.f, 0.f}, s1 = {0.f, 0.f, 0.f, 0.f};
    __builtin_amdgcn_s_setprio(1);
#pragma unroll
    for (int dc = 0; dc < 4; ++dc) {
      const int dblk = dc * 4 + kpart;
      bf8 k0f = *(const bf8*)(ksb + (dblk * 32 + col) * 8);
      bf8 k1f = *(const bf8*)(ksb + (dblk * 32 + 16 + col) * 8);
      s0 = MFMA16(qf[dc], k0f, s0);
      s1 = MFMA16(qf[dc], k1f, s1);
    }
    __builtin_amdgcn_s_setprio(0);
    float sa[4], sc[4], mxr[4], p0[4], p1[4];
    bool grow = false;
#pragma unroll
    for (int r = 0; r < 4; ++r) {
      float a = s0[r] * scale, c2 = s1[r] * scale;
      if (is_text) {
        const int qg = qw + rbase + r;
        if (kv0 + col > qg) a = -1e30f;
        if (kv0 + 16 + col > qg) c2 = -1e30f;
      }
      sa[r] = a; sc[r] = c2;
      float mx = fmaxf(a, c2);
      mx = fmaxf(mx, __shfl_xor(mx, 1));
      mx = fmaxf(mx, __shfl_xor(mx, 2));
      mx = fmaxf(mx, __shfl_xor(mx, 4));
      mx = fmaxf(mx, __shfl_xor(mx, 8));
      mxr[r] = mx;
      grow |= (mx > m_r[r] + 8.f);
    }
    if (__any(grow)) {  // full rescale path
      float fr[4];
#pragma unroll
      for (int r = 0; r < 4; ++r) {
        const float mn = fmaxf(m_r[r], mxr[r]);
        fr[r] = __expf(m_r[r] - mn);
        m_r[r] = mn;
        p0[r] = __expf(sa[r] - mn);
        p1[r] = __expf(sc[r] - mn);
        float ps = p0[r] + p1[r];
        ps += __shfl_xor(ps, 1);
        ps += __shfl_xor(ps, 2);
        ps += __shfl_xor(ps, 4);
        ps += __shfl_xor(ps, 8);
        l_r[r] = l_r[r] * fr[r] + ps;
      }
#pragma unroll
      for (int df = 0; df < 8; ++df) {
        o[df][0] *= fr[0]; o[df][1] *= fr[1];
        o[df][2] *= fr[2]; o[df][3] *= fr[3];
      }
    } else {  // defer-max: keep m, skip O-rescale (P bounded by e^8)
#pragma unroll
      for (int r = 0; r < 4; ++r) {
        p0[r] = __expf(sa[r] - m_r[r]);
        p1[r] = __expf(sc[r] - m_r[r]);
        float ps = p0[r] + p1[r];
        ps += __shfl_xor(ps, 1);
        ps += __shfl_xor(ps, 2);
        ps += __shfl_xor(ps, 4);
        ps += __shfl_xor(ps, 8);
        l_r[r] += ps;
      }
    }
#pragma unroll
    for (int r = 0; r < 4; ++r) {
      pw[(rbase + r) * 72 + col] = f2bf1(p0[r]);
      pw[(rbase + r) * 72 + 16 + col] = f2bf1(p1[r]);
    }
    bf8 pa = *(const bf8*)(pw + col * 72 + kpart * 8);
    __builtin_amdgcn_s_setprio(1);
#pragma unroll
    for (int df = 0; df < 8; ++df) {
      bf8 vf = *(const bf8*)(vsb + (kpart * 128 + df * 16 + col) * 8);
      o[df] = MFMA16(pa, vf, o[df]);
    }
    __builtin_amdgcn_s_setprio(0);
    cur ^= 1;
  }
#undef ASTAGE
  float inv[4];
#pragma unroll
  for (int r = 0; r < 4; ++r) inv[r] = 1.f / l_r[r];
  u16* ob = aob + (size_t)(b * 1024 + qw + rbase) * 2048 + h * 128 + col;
#pragma unroll
  for (int df = 0; df < 8; ++df)
#pragma unroll
    for (int r = 0; r < 4; ++r)
      ob[(size_t)r * 2048 + df * 16] = f2bf1(o[df][r] * inv[r]);
}

// ---------------------------------------------------------------------------
extern "C" void kernel_launch(void* const* d_in, const int* in_sizes, int n_in,
                              void* d_out, int out_size, void* d_ws,
                              size_t ws_size, hipStream_t stream) {
  const float* hs = (const float*)d_in[0];
  const float* img = (const float*)d_in[1];
  const float* wq = (const float*)d_in[2];
  const float* wk = (const float*)d_in[3];
  const float* wv = (const float*)d_in[4];
  const float* wo = (const float*)d_in[5];
  const float* cdw = (const float*)d_in[6];
  const float* ln1w = (const float*)d_in[7];
  const float* ln1b = (const float*)d_in[8];
  const float* plrw = (const float*)d_in[9];
  const float* piw = (const float*)d_in[10];
  const float* pib = (const float*)d_in[11];
  const float* ln2w = (const float*)d_in[12];
  const float* ln2b = (const float*)d_in[13];
  const float* offw = (const float*)d_in[14];
  const float* khw = (const float*)d_in[15];
  const float* khb = (const float*)d_in[16];
  const float* vhw = (const float*)d_in[17];
  const float* vhb = (const float*)d_in[18];
  float* outp = (float*)d_out;

  u16* wsp = (u16*)d_ws;
  const size_t SZ = 4194304;  // 2048*2048
  u16* hs_bf = wsp;
  u16* wq_bf = wsp + SZ;  // reused as aob_bf after gemm<0>
  u16* wk_bf = wsp + 2 * SZ;
  u16* wv_bf = wsp + 3 * SZ;
  u16* wo_bf = wsp + 4 * SZ;
  u16* khw_bf = wsp + 5 * SZ;
  u16* vhw_bf = wsp + 6 * SZ;
  u16* qb_bf = wsp + 7 * SZ;
  u16* samp_bf = wsp + 8 * SZ;       // 1152*2048
  u16* kg = wsp + 8 * SZ + 2359296;  // 2*16*1600*128
  u16* vg = kg + 6553600;
  float* lrb = (float*)kg;  // fp32 scratch overlaps kg/vg (dead before gemms)
  float* x1b = lrb + 2359296;
  float* x2b = x1b + 2359296;
  float* poolb = x2b + 294912;
  float* gb = poolb + 4096;
  float* posb = (float*)(vg + 6553600);
  u16* aob_bf = wq_bf;

  dim3 blk(256);
  // ---- offset network ----
  build_lr<<<dim3((B * G * CD * K) / 256), blk, 0, stream>>>(hs, lrb);
  pool_lr<<<dim3((B * G * CD) / 4), blk, 0, stream>>>(lrb, poolb);
  dwconv_silu<<<dim3((B * G * CD * K) / 256), blk, 0, stream>>>(lrb, cdw, x1b);
  ln_c512<<<dim3(B * G * 9), blk, 0, stream>>>(x1b, ln1w, ln1b);
  proj64<<<dim3(B * G * 8), dim3(576), 0, stream>>>(x1b, plrw, x2b);
  gate_k<<<dim3((B * G * INTER) / 64), dim3(64), 0, stream>>>(poolb, piw, pib,
                                                              gb);
  ln2_off_pos<<<dim3((B * G * K) / 4), blk, 0, stream>>>(x2b, gb, ln2w, ln2b,
                                                         offw, posb);
  sample_k<<<dim3(B * K), blk, 0, stream>>>(img, posb, samp_bf);

  // ---- bf16 conversions (fused) ----
  f2bf_k7<<<dim3(SZ / 4 / 256, 7), blk, 0, stream>>>(
      hs, wq, wk, wv, wo, khw, vhw, hs_bf, wq_bf, wk_bf, wv_bf, wo_bf, khw_bf,
      vhw_bf);

  // ---- MFMA GEMMs ----
  gemm_mf<0><<<dim3(48, 16), blk, 0, stream>>>(hs_bf, wq_bf, wk_bf, wv_bf,
                                               nullptr, nullptr, qb_bf, kg, vg,
                                               nullptr);
  gemm_mf<1><<<dim3(32, 9), blk, 0, stream>>>(samp_bf, khw_bf, vhw_bf, nullptr,
                                              khb, vhb, nullptr, kg, vg,
                                              nullptr);
  // ---- attention ----
  attn_mfma<<<dim3(512), blk, 0, stream>>>(qb_bf, kg, vg, aob_bf);
  // ---- output projection ----
  gemm_mf<2><<<dim3(16, 16), blk, 0, stream>>>(aob_bf, wo_bf, nullptr, nullptr,
                                               nullptr, nullptr, nullptr,
                                               nullptr, nullptr, outp);
}